// Round 10
// baseline (336.294 us; speedup 1.0000x reference)
//
#include <hip/hip_runtime.h>

#define TT 4
#define NN 50000
#define DH 64
#define EE 800000
#define BN_EPS 1e-5f
#define NB 196          // ceil(NN/256) scan blocks
#define G1 64           // prep blocks per t
#define G2 256          // blocks for stats_avg
#define RB 782          // k_rank grid-stride blocks (782*256 = 200192)

typedef __attribute__((ext_vector_type(8))) short short8;
typedef __attribute__((ext_vector_type(4))) float floatx4;

// ---------------- ws layout (byte offsets) ----------------
#define WS_DEG      0          // 50000 i -> 200000
#define WS_FLAGS    200704     // 196 i (lookback flags)
#define WS_ROWSTART 201728     // 50001 i
#define WS_PX       401920     // [4][G1][64] f = 65536
#define WS_PX2      467456     // 65536
#define WS_PA       532992     // [G2][64] f = 65536
#define WS_PA2      598528     // 65536
#define WS_W1EFF    664064     // 12288 bf16 = 24576
#define WS_B1EFF    688640     // 64 f
#define WS_PACKED   1048576    // 800000 int2 = 6.4 MB
#define WS_XB       8388608    // xb[n][4][64] bf16 = 25.6 MB
#define WS_AVGB     34078720   // avgb[n][4][64] bf16 = 25.6 MB
#define WS_RANK     34078720   // 800000 i (aliases avgb; dead before k_agg writes)

__device__ __forceinline__ unsigned short f2b(float f) {
    unsigned int u = __float_as_uint(f);
    unsigned int r = (u + 0x7FFFu + ((u >> 16) & 1u)) >> 16;
    return (unsigned short)r;
}
__device__ __forceinline__ float b2f(unsigned short u) {
    return __uint_as_float((unsigned int)u << 16);
}

// x[t][n][c] fp32 -> xb[n][t][c] bf16 + per-(t,c) stats partials; zeroes deg+flags
__global__ __launch_bounds__(256) void k_prep_stats(
    const float* __restrict__ x, unsigned short* __restrict__ xb,
    float* __restrict__ PX, float* __restrict__ PX2,
    int* __restrict__ deg, int* __restrict__ flags) {
    int t = blockIdx.y;
    int tid = threadIdx.x;
    int pb = t * G1 + blockIdx.x;              // 0..255
    int gid = pb * 256 + tid;
    if (gid < NN) deg[gid] = 0;
    else if (gid < NN + NB) flags[gid - NN] = 0;

    int g = blockIdx.x * 256 + tid;
    const floatx4* xt = (const floatx4*)(x + (size_t)t * NN * 64);
    float s[4] = {0.f, 0.f, 0.f, 0.f}, s2[4] = {0.f, 0.f, 0.f, 0.f};
    for (int v = g; v < NN * 16; v += G1 * 256) {     // stride mult of 16 -> c-group fixed
        floatx4 d = __builtin_nontemporal_load(&xt[v]); // x never re-read
        ushort4 o;
        o.x = f2b(d.x); o.y = f2b(d.y); o.z = f2b(d.z); o.w = f2b(d.w);
        int n = v >> 4, cg = (v & 15) * 4;
        *(ushort4*)(xb + (size_t)n * 256 + t * 64 + cg) = o;
        s[0] += d.x; s2[0] += d.x * d.x;
        s[1] += d.y; s2[1] += d.y * d.y;
        s[2] += d.z; s2[2] += d.z * d.z;
        s[3] += d.w; s2[3] += d.w * d.w;
    }
    __shared__ float ls[256 * 4], ls2[256 * 4];
#pragma unroll
    for (int j = 0; j < 4; ++j) { ls[tid * 4 + j] = s[j]; ls2[tid * 4 + j] = s2[j]; }
    __syncthreads();
    if (tid < 64) {
        int g16 = tid >> 2, comp = tid & 3;
        float rs = 0.f, rs2 = 0.f;
#pragma unroll
        for (int k = 0; k < 16; ++k) {
            int j = g16 + 16 * k;
            rs += ls[j * 4 + comp]; rs2 += ls2[j * 4 + comp];
        }
        int slot = (t * G1 + blockIdx.x) * 64 + tid;
        PX[slot] = rs; PX2[slot] = rs2;
    }
}

// grid-stride rank: 4 independent atomics in flight per thread
__global__ __launch_bounds__(256) void k_rank(const int* __restrict__ dst,
                                              int* __restrict__ deg,
                                              int* __restrict__ rank) {
    const int S = RB * 256;
    int e0 = blockIdx.x * 256 + threadIdx.x;
    int e1 = e0 + S, e2 = e0 + 2 * S, e3 = e0 + 3 * S;
    int d0 = dst[e0], d1 = dst[e1], d2 = dst[e2];
    int d3 = (e3 < EE) ? dst[e3] : 0;
    int r0 = atomicAdd(&deg[d0], 1);
    int r1 = atomicAdd(&deg[d1], 1);
    int r2 = atomicAdd(&deg[d2], 1);
    int r3 = (e3 < EE) ? atomicAdd(&deg[d3], 1) : 0;
    rank[e0] = r0; rank[e1] = r1; rank[e2] = r2;
    if (e3 < EE) rank[e3] = r3;
}

// one-kernel exclusive scan via decoupled lookback (value rides the atomic)
__global__ __launch_bounds__(256) void k_scan_lb(
    const int* __restrict__ deg, int* __restrict__ flags,
    int* __restrict__ row_start) {
    int b = blockIdx.x, tid = threadIdx.x;
    int i = b * 256 + tid;
    int v = (i < NN) ? deg[i] : 0;
    __shared__ int ls[256];
    ls[tid] = v;
    __syncthreads();
    for (int off = 1; off < 256; off <<= 1) {
        int t = (tid >= off) ? ls[tid - off] : 0;
        __syncthreads();
        ls[tid] += t;
        __syncthreads();
    }
    int incl = ls[tid];
    if (tid == 0) atomicExch(&flags[b], ls[255] + 1);   // publish aggregate ASAP
    __shared__ int pre_s;
    if (tid == 0) pre_s = 0;
    __syncthreads();
    if (tid < b) {                                      // b <= 195 < 256: parallel poll
        int f;
        do { f = atomicAdd(&flags[tid], 0); } while (f == 0);
        atomicAdd(&pre_s, f - 1);
    }
    __syncthreads();
    int excl = pre_s + incl - v;
    if (i < NN) row_start[i] = excl;
    if (i == NN - 1) row_start[NN] = excl + v;
}

// atomic-free CSR fill: position = row_start[dst] + rank
__global__ void k_fill2(const int* __restrict__ src, const int* __restrict__ dst,
                        const float* __restrict__ ew, const int* __restrict__ rank,
                        const int* __restrict__ row_start, int2* __restrict__ packed) {
    int e = blockIdx.x * 256 + threadIdx.x;
    if (e < EE) {
        int p = row_start[dst[e]] + rank[e];
        packed[p] = make_int2(src[e], __float_as_int(ew[e]));
    }
}

// one wave per node. Half-wave per edge: lanes 0-31 edge e, 32-63 edge e+1.
// Lane li (0-31): channels (li&7)*8..+7 of t = li>>3; one short8 (16 B) per edge.
// Edge payload xb[src][0..3][0..63] = 512 B contiguous (node-major layout).
__global__ __launch_bounds__(256) void k_agg(
    const unsigned short* __restrict__ xb, const int2* __restrict__ packed,
    const int* __restrict__ row_start, unsigned short* __restrict__ avgb) {
    int wv = __builtin_amdgcn_readfirstlane(threadIdx.x >> 6);
    int n = blockIdx.x * 4 + wv;
    int l = threadIdx.x & 63;
    int ep = l >> 5;                    // which edge of the pair
    int li = l & 31;                    // position within edge payload
    int co = li * 8;                    // short offset into the 256-short node block
    int rs = row_start[n], re = row_start[n + 1];
    float a[8];
#pragma unroll
    for (int k = 0; k < 8; ++k) a[k] = 0.f;
    float wsum = 0.f;
    int e = rs;
    for (; e + 8 <= re; e += 8) {
        int2 p[4];
        short8 v[4];
#pragma unroll
        for (int j = 0; j < 4; ++j) p[j] = packed[e + 2 * j + ep];
#pragma unroll
        for (int j = 0; j < 4; ++j)
            v[j] = *(const short8*)(xb + (size_t)p[j].x * 256 + co);
#pragma unroll
        for (int j = 0; j < 4; ++j) {
            float w = __int_as_float(p[j].y);
            wsum += w;
#pragma unroll
            for (int k = 0; k < 8; ++k)
                a[k] = fmaf(w, b2f((unsigned short)v[j][k]), a[k]);
        }
    }
    for (; e < re; e += 2) {
        int ee = e + ep;
        if (ee < re) {
            int2 p0 = packed[ee];
            float w = __int_as_float(p0.y);
            short8 v0 = *(const short8*)(xb + (size_t)p0.x * 256 + co);
            wsum += w;
#pragma unroll
            for (int k = 0; k < 8; ++k)
                a[k] = fmaf(w, b2f((unsigned short)v0[k]), a[k]);
        }
    }
    // combine the two half-wave accumulators (lane l <-> l^32)
#pragma unroll
    for (int k = 0; k < 8; ++k) a[k] += __shfl_xor(a[k], 32, 64);
    wsum += __shfl_xor(wsum, 32, 64);
    float rz = (wsum == 0.f) ? 1.f : (1.f / wsum);
    if (ep == 0) {
        short8 o;
#pragma unroll
        for (int k = 0; k < 8; ++k) o[k] = (short)f2b(a[k] * rz);
        *(short8*)(avgb + (size_t)n * 256 + co) = o;   // 512 B contiguous per wave
    }
}

// per-c sum/sumsq partials of avg (bf16 [n][4][64]), short8 loads
__global__ __launch_bounds__(256) void k_stats_avg(
    const unsigned short* __restrict__ avgb, float* __restrict__ PA,
    float* __restrict__ PA2) {
    int tid = threadIdx.x;
    int g = blockIdx.x * 256 + tid;
    const short8* av = (const short8*)avgb;
    float s[8], s2[8];
#pragma unroll
    for (int j = 0; j < 8; ++j) { s[j] = 0.f; s2[j] = 0.f; }
    for (int v = g; v < TT * NN * 8; v += G2 * 256) {  // c-group = (v%8)*8, fixed
        short8 d = av[v];
#pragma unroll
        for (int j = 0; j < 8; ++j) {
            float f = b2f((unsigned short)d[j]);
            s[j] += f; s2[j] += f * f;
        }
    }
    __shared__ float ls[256 * 8], ls2[256 * 8];
#pragma unroll
    for (int j = 0; j < 8; ++j) { ls[tid * 8 + j] = s[j]; ls2[tid * 8 + j] = s2[j]; }
    __syncthreads();
    if (tid < 64) {
        int g8 = tid >> 3, comp = tid & 7;
        float rs = 0.f, rs2 = 0.f;
#pragma unroll
        for (int k = 0; k < 32; ++k) {
            int j = g8 + 8 * k;
            rs += ls[j * 8 + comp]; rs2 += ls2[j * 8 + comp];
        }
        PA[blockIdx.x * 64 + tid] = rs;
        PA2[blockIdx.x * 64 + tid] = rs2;
    }
}

// stage-2 reduce + BN fold into bf16 W1eff / fp32 b1eff
__global__ void k_fold(const float* __restrict__ W1, const float* __restrict__ b1,
                       const float* __restrict__ gamma, const float* __restrict__ beta,
                       const float* __restrict__ PX, const float* __restrict__ PX2,
                       const float* __restrict__ PA, const float* __restrict__ PA2,
                       unsigned short* __restrict__ W1eff, float* __restrict__ b1eff) {
    __shared__ float gS[192], hS[192];
    int c = threadIdx.x;                        // 192 threads
    const float inv = 1.0f / (float)(TT * NN);
    if (c < 192) {
        float s = 0.f, s2 = 0.f;
        if (c < 64) {
            for (int i = 0; i < TT * G1; ++i) { s += PX[i * 64 + c]; s2 += PX2[i * 64 + c]; }
        } else if (c < 128) {
            int cc = c - 64;                    // prev: t=0..2 only
            for (int i = 0; i < (TT - 1) * G1; ++i) { s += PX[i * 64 + cc]; s2 += PX2[i * 64 + cc]; }
        } else {
            int cc = c - 128;
            for (int i = 0; i < G2; ++i) { s += PA[i * 64 + cc]; s2 += PA2[i * 64 + cc]; }
        }
        float mu = s * inv, ex2 = s2 * inv;
        float var = ex2 - mu * mu;
        float g = gamma[c] / sqrtf(var + BN_EPS);
        gS[c] = g;
        hS[c] = beta[c] - mu * g;
    }
    __syncthreads();
    for (int i = threadIdx.x; i < 64 * 192; i += blockDim.x) {
        int cc = i % 192;
        W1eff[i] = f2b(W1[i] * gS[cc]);
    }
    if (threadIdx.x < 64) {
        int o = threadIdx.x;
        float acc = b1[o];
        for (int cc = 0; cc < 192; ++cc) acc += hS[cc] * W1[o * 192 + cc];
        b1eff[o] = acc;
    }
}

// MFMA GEMM: block = 4 waves, wave = 16 rows x 64 outs (4 col-tiles), K=192.
// Row r = t*NN + n; each wave's 16 rows share t (NN % 16 == 0).
__global__ __launch_bounds__(256) void k_main(
    const unsigned short* __restrict__ xb, const unsigned short* __restrict__ avgb,
    const unsigned short* __restrict__ Wb, const float* __restrict__ bias,
    float* __restrict__ out) {
    int wave = threadIdx.x >> 6;
    int lane = threadIdx.x & 63;
    int r0 = blockIdx.x * 64 + wave * 16;
    int t0 = r0 / NN;
    int n0 = r0 - t0 * NN;
    int m = lane & 15;
    int q = lane >> 4;

    const unsigned short* xrow = xb   + (size_t)(n0 + m) * 256 + t0 * 64 + q * 8;
    const unsigned short* arow = avgb + (size_t)(n0 + m) * 256 + t0 * 64 + q * 8;
    bool has_prev = (t0 > 0);

    floatx4 acc[4];
#pragma unroll
    for (int ct = 0; ct < 4; ++ct) acc[ct] = (floatx4){0.f, 0.f, 0.f, 0.f};

    const short8 zf = (short8){0, 0, 0, 0, 0, 0, 0, 0};

#pragma unroll
    for (int kc = 0; kc < 6; ++kc) {
        short8 a;
        if (kc < 2) {
            a = *(const short8*)(xrow + kc * 32);
        } else if (kc < 4) {
            a = has_prev ? *(const short8*)(xrow - 64 + (kc - 2) * 32) : zf;
        } else {
            a = *(const short8*)(arow + (kc - 4) * 32);
        }
#pragma unroll
        for (int ct = 0; ct < 4; ++ct) {
            short8 b = *(const short8*)(Wb + (size_t)(ct * 16 + m) * 192 + kc * 32 + q * 8);
            acc[ct] = __builtin_amdgcn_mfma_f32_16x16x32_bf16(a, b, acc[ct], 0, 0, 0);
        }
    }

#pragma unroll
    for (int ct = 0; ct < 4; ++ct) {
        float bv = bias[ct * 16 + m];
#pragma unroll
        for (int i = 0; i < 4; ++i) {
            int row = q * 4 + i;
            __builtin_nontemporal_store(fmaxf(acc[ct][i] + bv, 0.f),
                                        &out[(size_t)(r0 + row) * 64 + ct * 16 + m]);
        }
    }
}

extern "C" void kernel_launch(void* const* d_in, const int* in_sizes, int n_in,
                              void* d_out, int out_size, void* d_ws, size_t ws_size,
                              hipStream_t stream) {
    const float* x     = (const float*)d_in[0];
    const float* ew    = (const float*)d_in[1];
    const float* W1    = (const float*)d_in[2];
    const float* b1    = (const float*)d_in[3];
    const float* gamma = (const float*)d_in[4];
    const float* beta  = (const float*)d_in[5];
    const int*   src   = (const int*)d_in[6];
    const int*   dst   = (const int*)d_in[7];
    float* out = (float*)d_out;
    char*  ws  = (char*)d_ws;

    int*   deg      = (int*)(ws + WS_DEG);
    int*   flags    = (int*)(ws + WS_FLAGS);
    int*   row_start= (int*)(ws + WS_ROWSTART);
    float* PX       = (float*)(ws + WS_PX);
    float* PX2      = (float*)(ws + WS_PX2);
    float* PA       = (float*)(ws + WS_PA);
    float* PA2      = (float*)(ws + WS_PA2);
    unsigned short* W1eff = (unsigned short*)(ws + WS_W1EFF);
    float* b1eff    = (float*)(ws + WS_B1EFF);
    int2*  packed   = (int2*)(ws + WS_PACKED);
    unsigned short* xb   = (unsigned short*)(ws + WS_XB);
    unsigned short* avgb = (unsigned short*)(ws + WS_AVGB);
    int*   rank     = (int*)(ws + WS_RANK);

    k_prep_stats<<<dim3(G1, TT), 256, 0, stream>>>(x, xb, PX, PX2, deg, flags);

    k_rank<<<RB, 256, 0, stream>>>(dst, deg, rank);

    k_scan_lb<<<NB, 256, 0, stream>>>(deg, flags, row_start);

    k_fill2<<<(EE + 255) / 256, 256, 0, stream>>>(src, dst, ew, rank, row_start, packed);

    k_agg<<<NN / 4, 256, 0, stream>>>(xb, packed, row_start, avgb);

    k_stats_avg<<<G2, 256, 0, stream>>>(avgb, PA, PA2);

    k_fold<<<1, 192, 0, stream>>>(W1, b1, gamma, beta, PX, PX2, PA, PA2, W1eff, b1eff);

    k_main<<<(TT * NN) / 64, 256, 0, stream>>>(xb, avgb, W1eff, b1eff, out);
}